// Round 8
// baseline (125.081 us; speedup 1.0000x reference)
//
#include <hip/hip_runtime.h>
#include <stdint.h>

#define TT 128
#define BB 4096
#define HH 64
#define BC 8      // batch rows per block (lanes 8-15 mirror 0-7) -> 512 blocks = 2/CU
#define HSTR 72   // h LDS row stride (bf16 shorts): 144B rows, 16B aligned

typedef __attribute__((ext_vector_type(8))) short bf16x8;
typedef __attribute__((ext_vector_type(4))) float f32x4;

static __device__ __forceinline__ short f2bf(float f) {  // RNE, one-time W convert
  uint32_t u = __builtin_bit_cast(uint32_t, f);
  u += 0x7fffu + ((u >> 16) & 1u);
  return (short)(u >> 16);
}
static __device__ __forceinline__ uint32_t cvtpk(float a, float b) {
  uint32_t r;
  asm("v_cvt_pk_bf16_f32 %0, %1, %2" : "=v"(r) : "v"(a), "v"(b));
  return r;  // lo16 = bf16(a), hi16 = bf16(b)
}
static __device__ __forceinline__ float rcpf(float x) { return __builtin_amdgcn_rcpf(x); }
static __device__ __forceinline__ float sigm(float x) { return rcpf(1.0f + __expf(-x)); }
static __device__ __forceinline__ float tanhf_fast(float x) {
  float e = __expf(2.0f * x);
  return 1.0f - 2.0f * rcpf(e + 1.0f);
}

// lgkm-only barrier: LDS ops drain, global prefetch loads stay in flight.
static __device__ __forceinline__ void block_sync_lds() {
  asm volatile("" ::: "memory");
  asm volatile("s_waitcnt lgkmcnt(0)" ::: "memory");
  __builtin_amdgcn_s_barrier();
  asm volatile("" ::: "memory");
}

__global__ __launch_bounds__(256) void gru_fused(
    const float* __restrict__ Hseq, const float* __restrict__ W_ih,
    const float* __restrict__ W_hh, const float* __restrict__ b_ih,
    const float* __restrict__ b_hh, const float* __restrict__ W_out,
    const float* __restrict__ b_out, float* __restrict__ out) {
  __shared__ __align__(16) short hsh[2][16][HSTR];  // bf16 h, double buffered
  __shared__ float psum[4][16];

  const int tid = threadIdx.x;
  const int w   = tid >> 6;    // wave 0..3 = gate-row chunk: j in [16w, 16w+16)
  const int l   = tid & 63;
  const int llo = l & 15;      // batch col (B/D frags) or gate row (A frag)
  const int lhi = l >> 4;
  const int k0  = lhi * 8;
  const int bbase = blockIdx.x * BC;
  const int brow  = llo & (BC - 1);  // mirrored batch row

  // ---- persistent W A-fragments (bf16): both W_ih and W_hh ----
  bf16x8 wih[3][2], whh[3][2];
#pragma unroll
  for (int c = 0; c < 3; ++c) {
    const int grow = 64 * c + 16 * w + llo;
#pragma unroll
    for (int hf = 0; hf < 2; ++hf) {
      const float* p = &W_ih[grow * 64 + hf * 32 + k0];
      const float* q = &W_hh[grow * 64 + hf * 32 + k0];
      bf16x8 a, b;
#pragma unroll
      for (int i = 0; i < 8; ++i) { a[i] = f2bf(p[i]); b[i] = f2bf(q[i]); }
      wih[c][hf] = a;
      whh[c][hf] = b;
    }
  }

  // ---- per-lane bias fragments (D rows j = 16w + 4*lhi + r) ----
  f32x4 biasR, biasZ, biasXN, biasHN;
#pragma unroll
  for (int r = 0; r < 4; ++r) {
    const int j = 16 * w + 4 * lhi + r;
    biasR[r]  = b_ih[j] + b_hh[j];
    biasZ[r]  = b_ih[64 + j] + b_hh[64 + j];
    biasXN[r] = b_ih[128 + j];
    biasHN[r] = b_hh[128 + j];
  }

  // zero h buffer 0 (h0 = 0)
  for (int i = tid; i < (16 * HSTR) / 2; i += 256) ((int*)hsh[0])[i] = 0;

  const float* xroot = Hseq + (size_t)(bbase + brow) * HH + k0;  // per-lane t=0 base

  // ---- prologue: c-tiles for t=0 from x[0]; prefetch xqA=x[1], xqB=x[2] ----
  f32x4 cR, cZ, cXN;  // x-side gate tiles for the NEXT consumed step (register-resident)
  {
    const f32x4* pv = (const f32x4*)xroot;
    f32x4 q0 = pv[0], q1 = pv[1], q2 = pv[8], q3 = pv[9];
    union { uint32_t u[4]; bf16x8 v; } x0, x1;
    x0.u[0] = cvtpk(q0[0], q0[1]); x0.u[1] = cvtpk(q0[2], q0[3]);
    x0.u[2] = cvtpk(q1[0], q1[1]); x0.u[3] = cvtpk(q1[2], q1[3]);
    x1.u[0] = cvtpk(q2[0], q2[1]); x1.u[1] = cvtpk(q2[2], q2[3]);
    x1.u[2] = cvtpk(q3[0], q3[1]); x1.u[3] = cvtpk(q3[2], q3[3]);
    cR  = __builtin_amdgcn_mfma_f32_16x16x32_bf16(wih[0][0], x0.v, biasR, 0, 0, 0);
    cR  = __builtin_amdgcn_mfma_f32_16x16x32_bf16(wih[0][1], x1.v, cR, 0, 0, 0);
    cZ  = __builtin_amdgcn_mfma_f32_16x16x32_bf16(wih[1][0], x0.v, biasZ, 0, 0, 0);
    cZ  = __builtin_amdgcn_mfma_f32_16x16x32_bf16(wih[1][1], x1.v, cZ, 0, 0, 0);
    cXN = __builtin_amdgcn_mfma_f32_16x16x32_bf16(wih[2][0], x0.v, biasXN, 0, 0, 0);
    cXN = __builtin_amdgcn_mfma_f32_16x16x32_bf16(wih[2][1], x1.v, cXN, 0, 0, 0);
  }
  f32x4 xqA0, xqA1, xqA2, xqA3, xqB0, xqB1, xqB2, xqB3;
  {
    const f32x4* pa = (const f32x4*)(xroot + (size_t)1 * BB * HH);
    xqA0 = pa[0]; xqA1 = pa[1]; xqA2 = pa[8]; xqA3 = pa[9];
    const f32x4* pb = (const f32x4*)(xroot + (size_t)2 * BB * HH);
    xqB0 = pb[0]; xqB1 = pb[1]; xqB2 = pb[8]; xqB3 = pb[9];
  }

  f32x4 hfp = {0.f, 0.f, 0.f, 0.f};  // fp32 h state (batch brow, 4 j's)
  block_sync_lds();

  // Step: consume c-tiles (x[t]); h-MFMAs on top; gates; publish h; then build
  // c-tiles for t+1 from XQ (= x[t+1], loaded 2 steps ago) and refill XQ<-x[TN].
#define STEP(RB, WB, XQ0, XQ1, XQ2, XQ3, TN)                                  \
  {                                                                           \
    const bf16x8 hb0 = *(const bf16x8*)&hsh[RB][llo][k0];                     \
    const bf16x8 hb1 = *(const bf16x8*)&hsh[RB][llo][k0 + 32];                \
    /* x-convert + refill in the lgkm shadow */                               \
    union { uint32_t u[4]; bf16x8 v; } x0, x1;                                \
    x0.u[0] = cvtpk(XQ0[0], XQ0[1]); x0.u[1] = cvtpk(XQ0[2], XQ0[3]);         \
    x0.u[2] = cvtpk(XQ1[0], XQ1[1]); x0.u[3] = cvtpk(XQ1[2], XQ1[3]);         \
    x1.u[0] = cvtpk(XQ2[0], XQ2[1]); x1.u[1] = cvtpk(XQ2[2], XQ2[3]);         \
    x1.u[2] = cvtpk(XQ3[0], XQ3[1]); x1.u[3] = cvtpk(XQ3[2], XQ3[3]);         \
    {                                                                         \
      const int tn = (TN) < TT ? (TN) : (TT - 1);                             \
      const f32x4* pv = (const f32x4*)(xroot + (size_t)tn * BB * HH);         \
      XQ0 = pv[0]; XQ1 = pv[1]; XQ2 = pv[8]; XQ3 = pv[9];                     \
    }                                                                         \
    /* h-side MFMAs consume current c-tiles as C-input */                     \
    f32x4 aR  = __builtin_amdgcn_mfma_f32_16x16x32_bf16(whh[0][0], hb0, cR, 0, 0, 0);   \
    aR        = __builtin_amdgcn_mfma_f32_16x16x32_bf16(whh[0][1], hb1, aR, 0, 0, 0);   \
    f32x4 aZ  = __builtin_amdgcn_mfma_f32_16x16x32_bf16(whh[1][0], hb0, cZ, 0, 0, 0);   \
    aZ        = __builtin_amdgcn_mfma_f32_16x16x32_bf16(whh[1][1], hb1, aZ, 0, 0, 0);   \
    f32x4 aHN = __builtin_amdgcn_mfma_f32_16x16x32_bf16(whh[2][0], hb0, biasHN, 0, 0, 0); \
    aHN       = __builtin_amdgcn_mfma_f32_16x16x32_bf16(whh[2][1], hb1, aHN, 0, 0, 0);  \
    /* gates + state update (fp32, lane-local) */                             \
    _Pragma("unroll")                                                         \
    for (int r = 0; r < 4; ++r) {                                             \
      const float rr = sigm(aR[r]);                                           \
      const float zz = sigm(aZ[r]);                                           \
      const float nn = tanhf_fast(cXN[r] + rr * aHN[r]);                      \
      hfp[r] = nn + zz * (hfp[r] - nn);                                       \
    }                                                                         \
    uint2 pk;                                                                 \
    pk.x = cvtpk(hfp[0], hfp[1]);                                             \
    pk.y = cvtpk(hfp[2], hfp[3]);                                             \
    *(uint2*)&hsh[WB][llo][16 * w + 4 * lhi] = pk;                            \
    /* rebuild c-tiles for next step (off the h critical path) */             \
    cR  = __builtin_amdgcn_mfma_f32_16x16x32_bf16(wih[0][0], x0.v, biasR, 0, 0, 0);     \
    cR  = __builtin_amdgcn_mfma_f32_16x16x32_bf16(wih[0][1], x1.v, cR, 0, 0, 0);        \
    cZ  = __builtin_amdgcn_mfma_f32_16x16x32_bf16(wih[1][0], x0.v, biasZ, 0, 0, 0);     \
    cZ  = __builtin_amdgcn_mfma_f32_16x16x32_bf16(wih[1][1], x1.v, cZ, 0, 0, 0);        \
    cXN = __builtin_amdgcn_mfma_f32_16x16x32_bf16(wih[2][0], x0.v, biasXN, 0, 0, 0);    \
    cXN = __builtin_amdgcn_mfma_f32_16x16x32_bf16(wih[2][1], x1.v, cXN, 0, 0, 0);       \
    block_sync_lds();                                                         \
  }

  for (int t = 0; t < TT; t += 2) {
    STEP(0, 1, xqA0, xqA1, xqA2, xqA3, t + 3);
    STEP(1, 0, xqB0, xqB1, xqB2, xqB3, t + 4);
  }
#undef STEP

  // ---- head: out[b] = h_last[b,:] . W_out + b_out ----
  {
    float part = 0.f;
#pragma unroll
    for (int r = 0; r < 4; ++r) part += hfp[r] * W_out[16 * w + 4 * lhi + r];
    part += __shfl_xor(part, 16);
    part += __shfl_xor(part, 32);
    if (lhi == 0) psum[w][llo] = part;
  }
  block_sync_lds();
  if (tid < BC)
    out[bbase + tid] = psum[0][tid] + psum[1][tid] + psum[2][tid] + psum[3][tid] + b_out[0];
}

extern "C" void kernel_launch(void* const* d_in, const int* in_sizes, int n_in,
                              void* d_out, int out_size, void* d_ws, size_t ws_size,
                              hipStream_t stream) {
  (void)in_sizes; (void)n_in; (void)d_ws; (void)ws_size; (void)out_size;
  const float* Hseq  = (const float*)d_in[0];
  const float* W_ih  = (const float*)d_in[1];
  const float* W_hh  = (const float*)d_in[2];
  const float* b_ih  = (const float*)d_in[3];
  const float* b_hh  = (const float*)d_in[4];
  const float* W_out = (const float*)d_in[5];
  const float* b_out = (const float*)d_in[6];
  float* out = (float*)d_out;
  gru_fused<<<BB / BC, 256, 0, stream>>>(Hseq, W_ih, W_hh, b_ih, b_hh, W_out, b_out, out);
}